// Round 4
// baseline (466.070 us; speedup 1.0000x reference)
//
#include <hip/hip_runtime.h>
#include <math.h>

#define NPOS 131072  // 8*128*128 spatial positions per (b, channel)

// ---------------------------------------------------------------------------
// k_pw: pointwise 64-out-channel group g: pre[b][o][p] = sum_k W[g*64+o][k] x[b][k][p]
// grid (1024, 2), block 128. 128-pos tiles: more blocks/CU than 256-pos (VGPR
// allows 5 waves/SIMD; 256-pos grid was stuck at 4 blocks/CU = 16 waves).
// ---------------------------------------------------------------------------
__global__ __launch_bounds__(128) void k_pw(const float* __restrict__ x,
                                            const float* __restrict__ w_qkv,
                                            float* __restrict__ pre, int g) {
  const int p = blockIdx.x * 128 + threadIdx.x;
  const int b = blockIdx.y;
  __shared__ __align__(16) float wlT[64 * 64];  // [k][o]
  for (int i = threadIdx.x; i < 4096; i += 128) {
    int o = i >> 6, k = i & 63;
    wlT[k * 64 + o] = w_qkv[(g * 64 + o) * 64 + k];
  }
  __syncthreads();
  float acc[64];
#pragma unroll
  for (int o = 0; o < 64; ++o) acc[o] = 0.f;
  const float* xb = x + ((size_t)b * 64) * NPOS + p;
  for (int k = 0; k < 64; ++k) {
    float xv = xb[(size_t)k * NPOS];
    const float4* w4 = (const float4*)&wlT[k * 64];
#pragma unroll
    for (int o4 = 0; o4 < 16; ++o4) {
      float4 wv = w4[o4];
      acc[o4 * 4 + 0] = fmaf(wv.x, xv, acc[o4 * 4 + 0]);
      acc[o4 * 4 + 1] = fmaf(wv.y, xv, acc[o4 * 4 + 1]);
      acc[o4 * 4 + 2] = fmaf(wv.z, xv, acc[o4 * 4 + 2]);
      acc[o4 * 4 + 3] = fmaf(wv.w, xv, acc[o4 * 4 + 3]);
    }
  }
  float* ob = pre + ((size_t)b * 64) * NPOS + p;
#pragma unroll
  for (int o = 0; o < 64; ++o) ob[(size_t)o * NPOS] = acc[o];
}

// ---------------------------------------------------------------------------
// k_dw: depthwise 3x3x3 SAME on a 64-channel group (weights rows g*64..+63).
// 1D grid 8192 with XCD swizzle: each XCD gets 1024 consecutive (z,y,x) ids =
// 16 whole channels -> halo re-reads between spatial neighbors hit that XCD's
// L2 instead of HBM. block (32,8).
// ---------------------------------------------------------------------------
__global__ __launch_bounds__(256) void k_dw(const float* __restrict__ pre,
                                            const float* __restrict__ w_dw,
                                            float* __restrict__ conv,
                                            float* __restrict__ nqp, int g) {
  const int id = blockIdx.x;                 // 0..8191
  const int sid = (id & 7) * 1024 + (id >> 3);  // XCD-contiguous chunks
  const int z = sid >> 6, r = sid & 63, by = r >> 2, bx = r & 3;
  const int b = z >> 6;
  const int c = z & 63;
  const int h0 = by * 8;
  const int w0 = bx * 32;
  __shared__ float t[10][10][34];
  __shared__ float red[4];
  const float* in = pre + ((size_t)b * 64 + c) * NPOS;
  const int tid = threadIdx.y * 32 + threadIdx.x;
  for (int i = tid; i < 3400; i += 256) {
    int wl = i % 34, r2 = i / 34, hl = r2 % 10, dl = r2 / 10;
    int dd = dl - 1, hh = h0 + hl - 1, ww = w0 + wl - 1;
    float v = 0.f;
    if (dd >= 0 && dd < 8 && hh >= 0 && hh < 128 && ww >= 0 && ww < 128)
      v = in[((size_t)dd * 128 + hh) * 128 + ww];
    t[dl][hl][wl] = v;
  }
  float wk[27];
#pragma unroll
  for (int i = 0; i < 27; ++i) wk[i] = w_dw[(g * 64 + c) * 27 + i];
  __syncthreads();
  const int wl = threadIdx.x, hl = threadIdx.y;
  float* outp = conv + ((size_t)b * 64 + c) * NPOS + (size_t)(h0 + hl) * 128 + (w0 + wl);
  float nsum = 0.f;
#pragma unroll
  for (int d = 0; d < 8; ++d) {
    float acc = 0.f;
#pragma unroll
    for (int kd = 0; kd < 3; ++kd)
#pragma unroll
      for (int kh = 0; kh < 3; ++kh)
#pragma unroll
        for (int kw = 0; kw < 3; ++kw)
          acc = fmaf(t[d + kd][hl + kh][wl + kw], wk[(kd * 3 + kh) * 3 + kw], acc);
    outp[(size_t)d * 128 * 128] = acc;
    nsum = fmaf(acc, acc, nsum);
  }
  if (nqp) {
    const int lane = tid & 63, wv = tid >> 6;
    float v = nsum;
    v += __shfl_down(v, 32); v += __shfl_down(v, 16); v += __shfl_down(v, 8);
    v += __shfl_down(v, 4);  v += __shfl_down(v, 2);  v += __shfl_down(v, 1);
    if (lane == 0) red[wv] = v;
    __syncthreads();
    if (tid == 0) {
      const int blk = by * 4 + bx;  // 64 spatial blocks per (b,c)
      nqp[((size_t)b * 64 + c) * 64 + blk] = red[0] + red[1] + red[2] + red[3];
    }
  }
}

// ---------------------------------------------------------------------------
// k_dwk_gram: depthwise-conv the 8 k-channels of one head over a d-HALF
// (4 of 8 planes) and fold against qconv -> partial S[8][8] + nk[8].
// 1D grid 2048 (= 16 bh * 2 dhalf * 64 spatial), XCD-swizzled. block (32,8).
// launch_bounds(256,1): let regalloc take ~160 VGPR (static need ~150) so
// NOTHING goes to AGPR shuffles (round 3: cap 116 -> accvgpr churn, 171us).
// ---------------------------------------------------------------------------
__global__ __launch_bounds__(256, 1) void k_dwk_gram(const float* __restrict__ kpre,
                                                     const float* __restrict__ qconv,
                                                     const float* __restrict__ w_dw,
                                                     float* __restrict__ partial4) {
  const int id = blockIdx.x;                  // 0..2047
  const int sid = (id & 7) * 256 + (id >> 3); // XCD-contiguous chunks
  const int slab = sid >> 6;                  // 0..31 = bh*2 + dh
  const int bh = slab >> 1, dh = slab & 1;
  const int r = sid & 63, by = r >> 2, bx = r & 3;
  const int b = bh >> 3, head = bh & 7;
  const int h0 = by * 8;
  const int w0 = bx * 32;
  const int d0 = dh * 4;
  const int tx = threadIdx.x, ty = threadIdx.y;
  const int tid = ty * 32 + tx;
  __shared__ float t[6][10][34];   // 6 d-planes (4 outputs + 2 halo)
  __shared__ float red[4][72];

  // q values at this block's positions: 8 channels x 4 d-planes
  float qv[32];  // [c][dloc] — static indices only
  {
    const float* qb = qconv + ((size_t)b * 64 + head * 8) * NPOS +
                      (size_t)d0 * 16384 + (size_t)(h0 + ty) * 128 + (w0 + tx);
#pragma unroll
    for (int c = 0; c < 8; ++c)
#pragma unroll
      for (int dl = 0; dl < 4; ++dl)
        qv[c * 4 + dl] = qb[(size_t)c * NPOS + (size_t)dl * 16384];
  }
  float S[64], nk[8];
#pragma unroll
  for (int i = 0; i < 64; ++i) S[i] = 0.f;

#pragma unroll
  for (int cc = 0; cc < 8; ++cc) {
    const int ch = head * 8 + cc;            // k-local channel 0..63
    const float* in = kpre + ((size_t)b * 64 + ch) * NPOS;
    __syncthreads();  // previous iteration done reading t
    for (int i = tid; i < 2040; i += 256) {
      int wl = i % 34, r2 = i / 34, hl = r2 % 10, dl = r2 / 10;
      int dd = d0 + dl - 1, hh = h0 + hl - 1, ww = w0 + wl - 1;
      float v = 0.f;
      if (dd >= 0 && dd < 8 && hh >= 0 && hh < 128 && ww >= 0 && ww < 128)
        v = in[((size_t)dd * 128 + hh) * 128 + ww];
      t[dl / 10 == 0 ? dl : dl][hl][wl] = v;  // dl in [0,6)
    }
    float wk[27];
#pragma unroll
    for (int i = 0; i < 27; ++i) wk[i] = w_dw[(64 + ch) * 27 + i];
    __syncthreads();
    float nkc = 0.f;
#pragma unroll
    for (int d = 0; d < 4; ++d) {
      float acc = 0.f;
#pragma unroll
      for (int kd = 0; kd < 3; ++kd)
#pragma unroll
        for (int kh = 0; kh < 3; ++kh)
#pragma unroll
          for (int kw = 0; kw < 3; ++kw)
            acc = fmaf(t[d + kd][ty + kh][tx + kw], wk[(kd * 3 + kh) * 3 + kw], acc);
      nkc = fmaf(acc, acc, nkc);
#pragma unroll
      for (int c = 0; c < 8; ++c)
        S[c * 8 + cc] = fmaf(qv[c * 4 + d], acc, S[c * 8 + cc]);
    }
    nk[cc] = nkc;
  }
  const int lane = tid & 63, wv = tid >> 6;
#pragma unroll
  for (int i = 0; i < 72; ++i) {
    float v = (i < 64) ? S[i] : nk[i - 64];
    v += __shfl_down(v, 32); v += __shfl_down(v, 16); v += __shfl_down(v, 8);
    v += __shfl_down(v, 4);  v += __shfl_down(v, 2);  v += __shfl_down(v, 1);
    if (lane == 0) red[wv][i] = v;
  }
  __syncthreads();
  if (tid < 72) {
    float s = red[0][tid] + red[1][tid] + red[2][tid] + red[3][tid];
    const int chunk = dh * 64 + by * 4 + bx;  // 128 chunks per bh
    partial4[(((size_t)bh) * 128 + chunk) * 72 + tid] = s;
  }
}

// ---------------------------------------------------------------------------
// k_attn: reduce partials (128 chunks), l2-normalize, temperature, softmax.
// grid 16, block 128.
// ---------------------------------------------------------------------------
__global__ void k_attn(const float* __restrict__ partial4, const float* __restrict__ nqp,
                       const float* __restrict__ temp, float* __restrict__ A) {
  const int bh = blockIdx.x;
  const int b = bh >> 3, head = bh & 7;
  const int tid = threadIdx.x;
  __shared__ float sums[80];
  if (tid < 72) {
    float s = 0.f;
    const float* pp = partial4 + (size_t)bh * 128 * 72 + tid;
    for (int j = 0; j < 128; ++j) s += pp[j * 72];
    sums[tid] = s;  // [0:64) S, [64:72) nk
  } else if (tid < 80) {
    const int c = tid - 72;
    float s = 0.f;
    const float* pp = nqp + ((size_t)b * 64 + head * 8 + c) * 64;
    for (int j = 0; j < 64; ++j) s += pp[j];
    sums[tid] = s;  // [72:80) nq
  }
  __syncthreads();
  if (tid < 8) {
    const int c = tid;
    float tp = temp[head];
    float qd = fmaxf(sqrtf(sums[72 + c]), 1e-12f);
    float vals[8];
    float mx = -1e30f;
#pragma unroll
    for (int e = 0; e < 8; ++e) {
      float kd = fmaxf(sqrtf(sums[64 + e]), 1e-12f);
      vals[e] = sums[c * 8 + e] / (qd * kd) * tp;
      mx = fmaxf(mx, vals[e]);
    }
    float den = 0.f;
#pragma unroll
    for (int e = 0; e < 8; ++e) { vals[e] = expf(vals[e] - mx); den += vals[e]; }
#pragma unroll
    for (int e = 0; e < 8; ++e) A[bh * 64 + c * 8 + e] = vals[e] / den;
  }
}

// ---------------------------------------------------------------------------
// k_M: M_b[o][hg*8+j] = sum_i Wp[o][hg*8+i] * A[b][hg][i][j].  grid 2, block 256.
// ---------------------------------------------------------------------------
__global__ void k_M(const float* __restrict__ w_proj, const float* __restrict__ A,
                    float* __restrict__ M) {
  const int b = blockIdx.x;
  for (int e = threadIdx.x; e < 4096; e += 256) {
    int o = e >> 6, gch = e & 63;
    int hg = gch >> 3, j = gch & 7;
    float s = 0.f;
#pragma unroll
    for (int i = 0; i < 8; ++i)
      s += w_proj[o * 64 + hg * 8 + i] * A[(b * 8 + hg) * 64 + i * 8 + j];
    M[b * 4096 + e] = s;
  }
}

// ---------------------------------------------------------------------------
// k_out: out[b][o][p] = sum_g M_b[o][g] * vconv[b][g][p]. grid (1024, 2), block 128.
// ---------------------------------------------------------------------------
__global__ __launch_bounds__(128) void k_out(const float* __restrict__ vconv,
                                             const float* __restrict__ M,
                                             float* __restrict__ out) {
  const int p = blockIdx.x * 128 + threadIdx.x;
  const int b = blockIdx.y;
  __shared__ __align__(16) float wlT[64 * 64];  // [g][o]
  for (int i = threadIdx.x; i < 4096; i += 128) {
    int o = i >> 6, g = i & 63;
    wlT[g * 64 + o] = M[b * 4096 + o * 64 + g];
  }
  __syncthreads();
  float acc[64];
#pragma unroll
  for (int o = 0; o < 64; ++o) acc[o] = 0.f;
  const float* vb = vconv + ((size_t)b * 64) * NPOS + p;
  for (int g = 0; g < 64; ++g) {
    float vv = vb[(size_t)g * NPOS];
    const float4* w4 = (const float4*)&wlT[g * 64];
#pragma unroll
    for (int o4 = 0; o4 < 16; ++o4) {
      float4 wv = w4[o4];
      acc[o4 * 4 + 0] = fmaf(wv.x, vv, acc[o4 * 4 + 0]);
      acc[o4 * 4 + 1] = fmaf(wv.y, vv, acc[o4 * 4 + 1]);
      acc[o4 * 4 + 2] = fmaf(wv.z, vv, acc[o4 * 4 + 2]);
      acc[o4 * 4 + 3] = fmaf(wv.w, vv, acc[o4 * 4 + 3]);
    }
  }
  float* ob = out + ((size_t)b * 64) * NPOS + p;
#pragma unroll
  for (int o = 0; o < 64; ++o) ob[(size_t)o * NPOS] = acc[o];
}

extern "C" void kernel_launch(void* const* d_in, const int* in_sizes, int n_in,
                              void* d_out, int out_size, void* d_ws, size_t ws_size,
                              hipStream_t stream) {
  const float* x      = (const float*)d_in[0];
  const float* w_qkv  = (const float*)d_in[1];
  const float* w_dw   = (const float*)d_in[2];
  const float* temp   = (const float*)d_in[3];
  const float* w_proj = (const float*)d_in[4];
  float* out = (float*)d_out;   // 2*64*131072 floats; also used as pre-conv staging
  float* ws  = (float*)d_ws;

  // workspace layout (floats) — total ~64.6 MiB
  float* conv_buf = ws;                       // 16,777,216  (qconv, later vconv)
  float* nqp      = conv_buf + 16777216ull;   // 8,192
  float* partial4 = nqp + 8192ull;            // 16*128*72 = 147,456
  float* Abuf     = partial4 + 147456ull;     // 1,024
  float* Mbuf     = Abuf + 1024ull;           // 8,192

  // q group: pointwise -> d_out, depthwise -> conv_buf (+ nq partials)
  k_pw<<<dim3(1024, 2), 128, 0, stream>>>(x, w_qkv, out, 0);
  k_dw<<<8192, dim3(32, 8), 0, stream>>>(out, w_dw, conv_buf, nqp, 0);
  // k group: pointwise -> d_out, depthwise fused with Gram vs qconv
  k_pw<<<dim3(1024, 2), 128, 0, stream>>>(x, w_qkv, out, 1);
  k_dwk_gram<<<2048, dim3(32, 8), 0, stream>>>(out, conv_buf, w_dw, partial4);
  // attention matrix + folded projection matrix
  k_attn<<<16, 128, 0, stream>>>(partial4, nqp, temp, Abuf);
  k_M<<<2, 256, 0, stream>>>(w_proj, Abuf, Mbuf);
  // v group: pointwise -> d_out, depthwise -> conv_buf, apply M -> d_out
  k_pw<<<dim3(1024, 2), 128, 0, stream>>>(x, w_qkv, out, 2);
  k_dw<<<8192, dim3(32, 8), 0, stream>>>(out, w_dw, conv_buf, nullptr, 2);
  k_out<<<dim3(1024, 2), 128, 0, stream>>>(conv_buf, Mbuf, out);
}

// Round 5
// 397.812 us; speedup vs baseline: 1.1716x; 1.1716x over previous
//
#include <hip/hip_runtime.h>
#include <math.h>

#define NPOS 131072  // 8*128*128 spatial positions per (b, channel)

// ---------------------------------------------------------------------------
// k_pw: pointwise 64-out-channel group g: pre[b][o][p] = sum_k W[g*64+o][k] x[b][k][p]
// grid (512, 2), block 256.
// ---------------------------------------------------------------------------
__global__ __launch_bounds__(256) void k_pw(const float* __restrict__ x,
                                            const float* __restrict__ w_qkv,
                                            float* __restrict__ pre, int g) {
  const int p = blockIdx.x * 256 + threadIdx.x;
  const int b = blockIdx.y;
  __shared__ __align__(16) float wlT[64 * 64];  // [k][o]
  for (int i = threadIdx.x; i < 4096; i += 256) {
    int o = i >> 6, k = i & 63;
    wlT[k * 64 + o] = w_qkv[(g * 64 + o) * 64 + k];
  }
  __syncthreads();
  float acc[64];
#pragma unroll
  for (int o = 0; o < 64; ++o) acc[o] = 0.f;
  const float* xb = x + ((size_t)b * 64) * NPOS + p;
  for (int k = 0; k < 64; ++k) {
    float xv = xb[(size_t)k * NPOS];
    const float4* w4 = (const float4*)&wlT[k * 64];
#pragma unroll
    for (int o4 = 0; o4 < 16; ++o4) {
      float4 wv = w4[o4];
      acc[o4 * 4 + 0] = fmaf(wv.x, xv, acc[o4 * 4 + 0]);
      acc[o4 * 4 + 1] = fmaf(wv.y, xv, acc[o4 * 4 + 1]);
      acc[o4 * 4 + 2] = fmaf(wv.z, xv, acc[o4 * 4 + 2]);
      acc[o4 * 4 + 3] = fmaf(wv.w, xv, acc[o4 * 4 + 3]);
    }
  }
  float* ob = pre + ((size_t)b * 64) * NPOS + p;
#pragma unroll
  for (int o = 0; o < 64; ++o) ob[(size_t)o * NPOS] = acc[o];
}

// ---------------------------------------------------------------------------
// k_dw: depthwise 3x3x3 SAME on a 64-channel group (weights rows g*64..+63).
// grid (4, 16, 128), block (32, 8). Optional per-block sum-of-squares -> nqp.
// ---------------------------------------------------------------------------
__global__ __launch_bounds__(256) void k_dw(const float* __restrict__ pre,
                                            const float* __restrict__ w_dw,
                                            float* __restrict__ conv,
                                            float* __restrict__ nqp, int g) {
  const int b = blockIdx.z >> 6;
  const int c = blockIdx.z & 63;
  const int h0 = blockIdx.y * 8;
  const int w0 = blockIdx.x * 32;
  __shared__ float t[10][10][34];
  __shared__ float red[4];
  const float* in = pre + ((size_t)b * 64 + c) * NPOS;
  const int tid = threadIdx.y * 32 + threadIdx.x;
  for (int i = tid; i < 3400; i += 256) {
    int wl = i % 34, r = i / 34, hl = r % 10, dl = r / 10;
    int dd = dl - 1, hh = h0 + hl - 1, ww = w0 + wl - 1;
    float v = 0.f;
    if (dd >= 0 && dd < 8 && hh >= 0 && hh < 128 && ww >= 0 && ww < 128)
      v = in[((size_t)dd * 128 + hh) * 128 + ww];
    t[dl][hl][wl] = v;
  }
  float wk[27];
#pragma unroll
  for (int i = 0; i < 27; ++i) wk[i] = w_dw[(g * 64 + c) * 27 + i];
  __syncthreads();
  const int wl = threadIdx.x, hl = threadIdx.y;
  float* outp = conv + ((size_t)b * 64 + c) * NPOS + (size_t)(h0 + hl) * 128 + (w0 + wl);
  float nsum = 0.f;
#pragma unroll
  for (int d = 0; d < 8; ++d) {
    float acc = 0.f;
#pragma unroll
    for (int kd = 0; kd < 3; ++kd)
#pragma unroll
      for (int kh = 0; kh < 3; ++kh)
#pragma unroll
        for (int kw = 0; kw < 3; ++kw)
          acc = fmaf(t[d + kd][hl + kh][wl + kw], wk[(kd * 3 + kh) * 3 + kw], acc);
    outp[(size_t)d * 128 * 128] = acc;
    nsum = fmaf(acc, acc, nsum);
  }
  if (nqp) {
    const int lane = tid & 63, wv = tid >> 6;
    float v = nsum;
    v += __shfl_down(v, 32); v += __shfl_down(v, 16); v += __shfl_down(v, 8);
    v += __shfl_down(v, 4);  v += __shfl_down(v, 2);  v += __shfl_down(v, 1);
    if (lane == 0) red[wv] = v;
    __syncthreads();
    if (tid == 0) {
      const int blk = blockIdx.y * 4 + blockIdx.x;  // 64 spatial blocks
      nqp[((size_t)b * 64 + c) * 64 + blk] = red[0] + red[1] + red[2] + red[3];
    }
  }
}

// ---------------------------------------------------------------------------
// k_dw_gram: depthwise-conv ONE k-channel e (= head*8 + ee) like k_dw, but
// instead of writing kconv, dot the conv output against the 8 q-channels of
// the same head (read from qconv; L2/L3-resident) -> per-block partial column
// S[c][e] (8 floats) + nk (1 float). Per-thread state ~60 VGPR: no spill.
// grid (4, 16, 128), block (32, 8).
// partial9[((b*64+ch)*64 + blk)*9 + i]: i<8 -> S_col[c=i], i==8 -> nk.
// ---------------------------------------------------------------------------
__global__ __launch_bounds__(256) void k_dw_gram(const float* __restrict__ kpre,
                                                 const float* __restrict__ qconv,
                                                 const float* __restrict__ w_dw,
                                                 float* __restrict__ partial9) {
  const int b = blockIdx.z >> 6;
  const int ch = blockIdx.z & 63;      // k-local channel = head*8 + ee
  const int head = ch >> 3;
  const int h0 = blockIdx.y * 8;
  const int w0 = blockIdx.x * 32;
  __shared__ float t[10][10][34];
  __shared__ float red[4][9];
  const float* in = kpre + ((size_t)b * 64 + ch) * NPOS;
  const int tid = threadIdx.y * 32 + threadIdx.x;
  for (int i = tid; i < 3400; i += 256) {
    int wl = i % 34, r = i / 34, hl = r % 10, dl = r / 10;
    int dd = dl - 1, hh = h0 + hl - 1, ww = w0 + wl - 1;
    float v = 0.f;
    if (dd >= 0 && dd < 8 && hh >= 0 && hh < 128 && ww >= 0 && ww < 128)
      v = in[((size_t)dd * 128 + hh) * 128 + ww];
    t[dl][hl][wl] = v;
  }
  float wk[27];
#pragma unroll
  for (int i = 0; i < 27; ++i) wk[i] = w_dw[(64 + ch) * 27 + i];
  __syncthreads();
  const int wl = threadIdx.x, hl = threadIdx.y;
  const float* qb = qconv + ((size_t)b * 64 + head * 8) * NPOS +
                    (size_t)(h0 + hl) * 128 + (w0 + wl);
  float S[8], nk = 0.f;
#pragma unroll
  for (int c = 0; c < 8; ++c) S[c] = 0.f;
#pragma unroll
  for (int d = 0; d < 8; ++d) {
    float acc = 0.f;
#pragma unroll
    for (int kd = 0; kd < 3; ++kd)
#pragma unroll
      for (int kh = 0; kh < 3; ++kh)
#pragma unroll
        for (int kw = 0; kw < 3; ++kw)
          acc = fmaf(t[d + kd][hl + kh][wl + kw], wk[(kd * 3 + kh) * 3 + kw], acc);
    nk = fmaf(acc, acc, nk);
    const float* qd = qb + (size_t)d * 16384;
#pragma unroll
    for (int c = 0; c < 8; ++c)
      S[c] = fmaf(qd[(size_t)c * NPOS], acc, S[c]);
  }
  const int lane = tid & 63, wv = tid >> 6;
#pragma unroll
  for (int i = 0; i < 9; ++i) {
    float v = (i < 8) ? S[i] : nk;
    v += __shfl_down(v, 32); v += __shfl_down(v, 16); v += __shfl_down(v, 8);
    v += __shfl_down(v, 4);  v += __shfl_down(v, 2);  v += __shfl_down(v, 1);
    if (lane == 0) red[wv][i] = v;
  }
  __syncthreads();
  if (tid < 9) {
    float s = red[0][tid] + red[1][tid] + red[2][tid] + red[3][tid];
    const int blk = blockIdx.y * 4 + blockIdx.x;  // 64 spatial blocks
    partial9[(((size_t)b * 64 + ch) * 64 + blk) * 9 + tid] = s;
  }
}

// ---------------------------------------------------------------------------
// k_attn: reduce partials, l2-normalize, temperature, softmax -> A[bh][c][e].
// grid 16, block 128.
// ---------------------------------------------------------------------------
__global__ void k_attn(const float* __restrict__ partial9, const float* __restrict__ nqp,
                       const float* __restrict__ temp, float* __restrict__ A) {
  const int bh = blockIdx.x;
  const int b = bh >> 3, head = bh & 7;
  const int tid = threadIdx.x;
  __shared__ float sums[80];
  if (tid < 64) {
    const int c = tid >> 3, e = tid & 7;
    float s = 0.f;
    const float* pp = partial9 + (((size_t)b * 64 + head * 8 + e) * 64) * 9 + c;
    for (int j = 0; j < 64; ++j) s += pp[j * 9];
    sums[c * 8 + e] = s;
  } else if (tid < 72) {
    const int e = tid - 64;
    float s = 0.f;
    const float* pp = partial9 + (((size_t)b * 64 + head * 8 + e) * 64) * 9 + 8;
    for (int j = 0; j < 64; ++j) s += pp[j * 9];
    sums[64 + e] = s;  // nk[e]
  } else if (tid < 80) {
    const int c = tid - 72;
    float s = 0.f;
    const float* pp = nqp + ((size_t)b * 64 + head * 8 + c) * 64;
    for (int j = 0; j < 64; ++j) s += pp[j];
    sums[72 + c] = s;  // nq[c]
  }
  __syncthreads();
  if (tid < 8) {
    const int c = tid;
    float tp = temp[head];
    float qd = fmaxf(sqrtf(sums[72 + c]), 1e-12f);
    float vals[8];
    float mx = -1e30f;
#pragma unroll
    for (int e = 0; e < 8; ++e) {
      float kd = fmaxf(sqrtf(sums[64 + e]), 1e-12f);
      vals[e] = sums[c * 8 + e] / (qd * kd) * tp;
      mx = fmaxf(mx, vals[e]);
    }
    float den = 0.f;
#pragma unroll
    for (int e = 0; e < 8; ++e) { vals[e] = expf(vals[e] - mx); den += vals[e]; }
#pragma unroll
    for (int e = 0; e < 8; ++e) A[bh * 64 + c * 8 + e] = vals[e] / den;
  }
}

// ---------------------------------------------------------------------------
// k_M: M_b[o][hg*8+j] = sum_i Wp[o][hg*8+i] * A[b][hg][i][j].  grid 2, block 256.
// ---------------------------------------------------------------------------
__global__ void k_M(const float* __restrict__ w_proj, const float* __restrict__ A,
                    float* __restrict__ M) {
  const int b = blockIdx.x;
  for (int e = threadIdx.x; e < 4096; e += 256) {
    int o = e >> 6, gch = e & 63;
    int hg = gch >> 3, j = gch & 7;
    float s = 0.f;
#pragma unroll
    for (int i = 0; i < 8; ++i)
      s += w_proj[o * 64 + hg * 8 + i] * A[(b * 8 + hg) * 64 + i * 8 + j];
    M[b * 4096 + e] = s;
  }
}

// ---------------------------------------------------------------------------
// k_out: out[b][o][p] = sum_g M_b[o][g] * vconv[b][g][p]. grid (512, 2), block 256.
// ---------------------------------------------------------------------------
__global__ __launch_bounds__(256) void k_out(const float* __restrict__ vconv,
                                             const float* __restrict__ M,
                                             float* __restrict__ out) {
  const int p = blockIdx.x * 256 + threadIdx.x;
  const int b = blockIdx.y;
  __shared__ __align__(16) float wlT[64 * 64];  // [g][o]
  for (int i = threadIdx.x; i < 4096; i += 256) {
    int o = i >> 6, g = i & 63;
    wlT[g * 64 + o] = M[b * 4096 + o * 64 + g];
  }
  __syncthreads();
  float acc[64];
#pragma unroll
  for (int o = 0; o < 64; ++o) acc[o] = 0.f;
  const float* vb = vconv + ((size_t)b * 64) * NPOS + p;
  for (int g = 0; g < 64; ++g) {
    float vv = vb[(size_t)g * NPOS];
    const float4* w4 = (const float4*)&wlT[g * 64];
#pragma unroll
    for (int o4 = 0; o4 < 16; ++o4) {
      float4 wv = w4[o4];
      acc[o4 * 4 + 0] = fmaf(wv.x, vv, acc[o4 * 4 + 0]);
      acc[o4 * 4 + 1] = fmaf(wv.y, vv, acc[o4 * 4 + 1]);
      acc[o4 * 4 + 2] = fmaf(wv.z, vv, acc[o4 * 4 + 2]);
      acc[o4 * 4 + 3] = fmaf(wv.w, vv, acc[o4 * 4 + 3]);
    }
  }
  float* ob = out + ((size_t)b * 64) * NPOS + p;
#pragma unroll
  for (int o = 0; o < 64; ++o) ob[(size_t)o * NPOS] = acc[o];
}

extern "C" void kernel_launch(void* const* d_in, const int* in_sizes, int n_in,
                              void* d_out, int out_size, void* d_ws, size_t ws_size,
                              hipStream_t stream) {
  const float* x      = (const float*)d_in[0];
  const float* w_qkv  = (const float*)d_in[1];
  const float* w_dw   = (const float*)d_in[2];
  const float* temp   = (const float*)d_in[3];
  const float* w_proj = (const float*)d_in[4];
  float* out = (float*)d_out;   // 2*64*131072 floats; also used as pre-conv staging
  float* ws  = (float*)d_ws;

  // workspace layout (floats) — total ~64.4 MiB
  float* conv_buf = ws;                       // 16,777,216  (qconv, later vconv)
  float* nqp      = conv_buf + 16777216ull;   // 8,192
  float* partial9 = nqp + 8192ull;            // 128*64*9 = 73,728
  float* Abuf     = partial9 + 73728ull;      // 1,024
  float* Mbuf     = Abuf + 1024ull;           // 8,192

  // q group: pointwise -> d_out, depthwise -> conv_buf (+ nq partials)
  k_pw<<<dim3(512, 2), 256, 0, stream>>>(x, w_qkv, out, 0);
  k_dw<<<dim3(4, 16, 128), dim3(32, 8), 0, stream>>>(out, w_dw, conv_buf, nqp, 0);
  // k group: pointwise -> d_out, depthwise fused with column-Gram vs qconv
  k_pw<<<dim3(512, 2), 256, 0, stream>>>(x, w_qkv, out, 1);
  k_dw_gram<<<dim3(4, 16, 128), dim3(32, 8), 0, stream>>>(out, conv_buf, w_dw, partial9);
  // attention matrix + folded projection matrix
  k_attn<<<16, 128, 0, stream>>>(partial9, nqp, temp, Abuf);
  k_M<<<2, 256, 0, stream>>>(w_proj, Abuf, Mbuf);
  // v group: pointwise -> d_out, depthwise -> conv_buf, apply M -> d_out
  k_pw<<<dim3(512, 2), 256, 0, stream>>>(x, w_qkv, out, 2);
  k_dw<<<dim3(4, 16, 128), dim3(32, 8), 0, stream>>>(out, w_dw, conv_buf, nullptr, 2);
  k_out<<<dim3(512, 2), 256, 0, stream>>>(conv_buf, Mbuf, out);
}

// Round 6
// 346.598 us; speedup vs baseline: 1.3447x; 1.1478x over previous
//
#include <hip/hip_runtime.h>
#include <math.h>

#define NPOS 131072  // 8*128*128 spatial positions per (b, channel)

// ---------------------------------------------------------------------------
// k_prep: transpose w_qkv [192 out][64 in] -> wT[3 g][64 k][64 o] so the
// pointwise kernels can read weight rows with wave-uniform (scalar) loads.
// ---------------------------------------------------------------------------
__global__ void k_prep(const float* __restrict__ w_qkv, float* __restrict__ wT) {
  for (int i = blockIdx.x * 256 + threadIdx.x; i < 12288; i += 512) {
    int g = i >> 12, r = i & 4095, k = r >> 6, o = r & 63;
    wT[i] = w_qkv[(g * 64 + o) * 64 + k];
  }
}

// ---------------------------------------------------------------------------
// k_pw: pre[b][o][p] = sum_k wTg[k][o] * x[b][k][p].  grid (512, 2), block 256.
// Weights via wave-uniform loads (SGPR operands) -> zero LDS traffic; the
// round-5 LDS version issued 1024 ds_read_b128/thread (LDS-issue-bound).
// ---------------------------------------------------------------------------
__global__ __launch_bounds__(256) void k_pw(const float* __restrict__ x,
                                            const float* __restrict__ wTg,
                                            float* __restrict__ pre) {
  const int p = blockIdx.x * 256 + threadIdx.x;
  const int b = blockIdx.y;
  float acc[64];
#pragma unroll
  for (int o = 0; o < 64; ++o) acc[o] = 0.f;
  const float* xb = x + ((size_t)b * 64) * NPOS + p;
  for (int k = 0; k < 64; ++k) {
    float xv = xb[(size_t)k * NPOS];
    const float* wr = wTg + (k << 6);   // wave-uniform row -> s_load
#pragma unroll
    for (int o = 0; o < 64; ++o) acc[o] = fmaf(wr[o], xv, acc[o]);
  }
  float* ob = pre + ((size_t)b * 64) * NPOS + p;
#pragma unroll
  for (int o = 0; o < 64; ++o) ob[(size_t)o * NPOS] = acc[o];
}

// ---------------------------------------------------------------------------
// stage_tile: load one channel's halo tile into LDS t[10][10][40].
// d-planes 0 and 9 are zero (depth halo), h halo handled by bounds check,
// w: center 32 floats at [4..35] via aligned float4 (w0 % 32 == 0), edges at
// [3] (w0-1) and [36] (w0+32) scalar. ~3.9 iterations/thread, all vector.
// ---------------------------------------------------------------------------
__device__ __forceinline__ void stage_tile(float (*t)[10][40], const float* __restrict__ in,
                                           int h0, int w0, int tid) {
  for (int i = tid; i < 800; i += 256) {
    int j = i & 7, row = i >> 3;          // 8 float4 per row, 100 rows
    int h = row % 10, dpl = row / 10;     // dpl 0..9 (= depth+1)
    int dd = dpl - 1, hh = h0 + h - 1;
    float4 v = make_float4(0.f, 0.f, 0.f, 0.f);
    if (dd >= 0 && dd < 8 && hh >= 0 && hh < 128)
      v = *(const float4*)&in[((size_t)dd * 128 + hh) * 128 + (w0 + j * 4)];
    *(float4*)&t[dpl][h][4 + j * 4] = v;
  }
  for (int i = tid; i < 200; i += 256) {
    int side = i & 1, row = i >> 1;
    int h = row % 10, dpl = row / 10;
    int dd = dpl - 1, hh = h0 + h - 1;
    int ww = side ? (w0 + 32) : (w0 - 1);
    float v = 0.f;
    if (dd >= 0 && dd < 8 && hh >= 0 && hh < 128 && ww >= 0 && ww < 128)
      v = in[((size_t)dd * 128 + hh) * 128 + ww];
    t[dpl][h][side ? 36 : 3] = v;
  }
}

// ---------------------------------------------------------------------------
// k_dw: depthwise 3x3x3 SAME on a 64-channel group (weights rows g*64..+63).
// grid (4, 16, 128), block (32, 8). Optional per-block sum-of-squares -> nqp.
// ---------------------------------------------------------------------------
__global__ __launch_bounds__(256) void k_dw(const float* __restrict__ pre,
                                            const float* __restrict__ w_dw,
                                            float* __restrict__ conv,
                                            float* __restrict__ nqp, int g) {
  const int b = blockIdx.z >> 6;
  const int c = blockIdx.z & 63;
  const int h0 = blockIdx.y * 8;
  const int w0 = blockIdx.x * 32;
  __shared__ float t[10][10][40];
  __shared__ float red[4];
  const int tid = threadIdx.y * 32 + threadIdx.x;
  stage_tile(t, pre + ((size_t)b * 64 + c) * NPOS, h0, w0, tid);
  float wk[27];
#pragma unroll
  for (int i = 0; i < 27; ++i) wk[i] = w_dw[(g * 64 + c) * 27 + i];  // uniform -> SGPR
  __syncthreads();
  const int wl = threadIdx.x, hl = threadIdx.y;
  float* outp = conv + ((size_t)b * 64 + c) * NPOS + (size_t)(h0 + hl) * 128 + (w0 + wl);
  float nsum = 0.f;
#pragma unroll
  for (int d = 0; d < 8; ++d) {
    float acc = 0.f;
#pragma unroll
    for (int kd = 0; kd < 3; ++kd)
#pragma unroll
      for (int kh = 0; kh < 3; ++kh)
#pragma unroll
        for (int kw = 0; kw < 3; ++kw)
          acc = fmaf(t[d + kd][hl + kh][3 + wl + kw], wk[(kd * 3 + kh) * 3 + kw], acc);
    outp[(size_t)d * 128 * 128] = acc;
    nsum = fmaf(acc, acc, nsum);
  }
  if (nqp) {
    const int lane = tid & 63, wv = tid >> 6;
    float v = nsum;
    v += __shfl_down(v, 32); v += __shfl_down(v, 16); v += __shfl_down(v, 8);
    v += __shfl_down(v, 4);  v += __shfl_down(v, 2);  v += __shfl_down(v, 1);
    if (lane == 0) red[wv] = v;
    __syncthreads();
    if (tid == 0) {
      const int blk = blockIdx.y * 4 + blockIdx.x;
      nqp[((size_t)b * 64 + c) * 64 + blk] = red[0] + red[1] + red[2] + red[3];
    }
  }
}

// ---------------------------------------------------------------------------
// k_dwk2: depthwise-conv TWO k-channels (ch0=2*cg, ch1=ch0+1; same head) and
// fold against the head's 8 q-channels -> partial columns S[c][ch{0,1}] + nk.
// The 64 q-loads/thread are shared by both channels (halves q L2/L3 traffic).
// grid (4, 16, 64 = b*32+cg), block (32, 8).
// ---------------------------------------------------------------------------
__global__ __launch_bounds__(256) void k_dwk2(const float* __restrict__ kpre,
                                              const float* __restrict__ qconv,
                                              const float* __restrict__ w_dw,
                                              float* __restrict__ partial9) {
  const int z = blockIdx.z;
  const int b = z >> 5, cg = z & 31;
  const int ch0 = cg * 2, ch1 = ch0 + 1;
  const int head = ch0 >> 3;
  const int h0 = blockIdx.y * 8;
  const int w0 = blockIdx.x * 32;
  const int tx = threadIdx.x, ty = threadIdx.y;
  const int tid = ty * 32 + tx;
  __shared__ float t0[10][10][40];
  __shared__ float t1[10][10][40];
  __shared__ float red[4][18];
  stage_tile(t0, kpre + ((size_t)b * 64 + ch0) * NPOS, h0, w0, tid);
  stage_tile(t1, kpre + ((size_t)b * 64 + ch1) * NPOS, h0, w0, tid);
  float wk0[27], wk1[27];
#pragma unroll
  for (int i = 0; i < 27; ++i) wk0[i] = w_dw[(64 + ch0) * 27 + i];  // uniform -> SGPR
#pragma unroll
  for (int i = 0; i < 27; ++i) wk1[i] = w_dw[(64 + ch1) * 27 + i];
  __syncthreads();
  float S0[8], S1[8], nk0 = 0.f, nk1 = 0.f;
#pragma unroll
  for (int i = 0; i < 8; ++i) { S0[i] = 0.f; S1[i] = 0.f; }
  const float* qb = qconv + ((size_t)b * 64 + head * 8) * NPOS +
                    (size_t)(h0 + ty) * 128 + (w0 + tx);
#pragma unroll
  for (int d = 0; d < 8; ++d) {
    float a0 = 0.f, a1 = 0.f;
#pragma unroll
    for (int kd = 0; kd < 3; ++kd)
#pragma unroll
      for (int kh = 0; kh < 3; ++kh)
#pragma unroll
        for (int kw = 0; kw < 3; ++kw) {
          float w0v = wk0[(kd * 3 + kh) * 3 + kw];
          float w1v = wk1[(kd * 3 + kh) * 3 + kw];
          a0 = fmaf(t0[d + kd][ty + kh][3 + tx + kw], w0v, a0);
          a1 = fmaf(t1[d + kd][ty + kh][3 + tx + kw], w1v, a1);
        }
    nk0 = fmaf(a0, a0, nk0);
    nk1 = fmaf(a1, a1, nk1);
    const float* qd = qb + (size_t)d * 16384;
#pragma unroll
    for (int c8 = 0; c8 < 8; ++c8) {
      float qv = qd[(size_t)c8 * NPOS];
      S0[c8] = fmaf(qv, a0, S0[c8]);
      S1[c8] = fmaf(qv, a1, S1[c8]);
    }
  }
  const int lane = tid & 63, wv = tid >> 6;
#pragma unroll
  for (int i = 0; i < 18; ++i) {
    float v = (i < 8) ? S0[i] : (i == 8) ? nk0 : (i < 17) ? S1[i - 9] : nk1;
    v += __shfl_down(v, 32); v += __shfl_down(v, 16); v += __shfl_down(v, 8);
    v += __shfl_down(v, 4);  v += __shfl_down(v, 2);  v += __shfl_down(v, 1);
    if (lane == 0) red[wv][i] = v;
  }
  __syncthreads();
  if (tid < 18) {
    float s = red[0][tid] + red[1][tid] + red[2][tid] + red[3][tid];
    const int ch = (tid < 9) ? ch0 : ch1;
    const int idx = (tid < 9) ? tid : tid - 9;
    const int blk = blockIdx.y * 4 + blockIdx.x;
    partial9[(((size_t)b * 64 + ch) * 64 + blk) * 9 + idx] = s;
  }
}

// ---------------------------------------------------------------------------
// k_attn: reduce partials, l2-normalize, temperature, softmax -> A[bh][c][e].
// grid 16, block 128.
// ---------------------------------------------------------------------------
__global__ void k_attn(const float* __restrict__ partial9, const float* __restrict__ nqp,
                       const float* __restrict__ temp, float* __restrict__ A) {
  const int bh = blockIdx.x;
  const int b = bh >> 3, head = bh & 7;
  const int tid = threadIdx.x;
  __shared__ float sums[80];
  if (tid < 64) {
    const int c = tid >> 3, e = tid & 7;
    float s = 0.f;
    const float* pp = partial9 + (((size_t)b * 64 + head * 8 + e) * 64) * 9 + c;
    for (int j = 0; j < 64; ++j) s += pp[j * 9];
    sums[c * 8 + e] = s;
  } else if (tid < 72) {
    const int e = tid - 64;
    float s = 0.f;
    const float* pp = partial9 + (((size_t)b * 64 + head * 8 + e) * 64) * 9 + 8;
    for (int j = 0; j < 64; ++j) s += pp[j * 9];
    sums[64 + e] = s;  // nk[e]
  } else if (tid < 80) {
    const int c = tid - 72;
    float s = 0.f;
    const float* pp = nqp + ((size_t)b * 64 + head * 8 + c) * 64;
    for (int j = 0; j < 64; ++j) s += pp[j];
    sums[72 + c] = s;  // nq[c]
  }
  __syncthreads();
  if (tid < 8) {
    const int c = tid;
    float tp = temp[head];
    float qd = fmaxf(sqrtf(sums[72 + c]), 1e-12f);
    float vals[8];
    float mx = -1e30f;
#pragma unroll
    for (int e = 0; e < 8; ++e) {
      float kd = fmaxf(sqrtf(sums[64 + e]), 1e-12f);
      vals[e] = sums[c * 8 + e] / (qd * kd) * tp;
      mx = fmaxf(mx, vals[e]);
    }
    float den = 0.f;
#pragma unroll
    for (int e = 0; e < 8; ++e) { vals[e] = expf(vals[e] - mx); den += vals[e]; }
#pragma unroll
    for (int e = 0; e < 8; ++e) A[bh * 64 + c * 8 + e] = vals[e] / den;
  }
}

// ---------------------------------------------------------------------------
// k_M: M_b[o][hg*8+j] = sum_i Wp[o][hg*8+i] * A[b][hg][i][j]; writes the
// transposed MT[b][g][o] for scalar-load consumption in k_out. grid 2, blk 256.
// ---------------------------------------------------------------------------
__global__ void k_M(const float* __restrict__ w_proj, const float* __restrict__ A,
                    float* __restrict__ MT) {
  const int b = blockIdx.x;
  for (int e = threadIdx.x; e < 4096; e += 256) {
    int o = e >> 6, gch = e & 63;
    int hg = gch >> 3, j = gch & 7;
    float s = 0.f;
#pragma unroll
    for (int i = 0; i < 8; ++i)
      s += w_proj[o * 64 + hg * 8 + i] * A[(b * 8 + hg) * 64 + i * 8 + j];
    MT[b * 4096 + gch * 64 + o] = s;
  }
}

// ---------------------------------------------------------------------------
// k_out: out[b][o][p] = sum_g MT[b][g][o] * vconv[b][g][p]. Same scalar-weight
// structure as k_pw. grid (512, 2), block 256.
// ---------------------------------------------------------------------------
__global__ __launch_bounds__(256) void k_out(const float* __restrict__ vconv,
                                             const float* __restrict__ MT,
                                             float* __restrict__ out) {
  const int p = blockIdx.x * 256 + threadIdx.x;
  const int b = blockIdx.y;
  float acc[64];
#pragma unroll
  for (int o = 0; o < 64; ++o) acc[o] = 0.f;
  const float* vb = vconv + ((size_t)b * 64) * NPOS + p;
  const float* Mb = MT + b * 4096;
  for (int g = 0; g < 64; ++g) {
    float vv = vb[(size_t)g * NPOS];
    const float* wr = Mb + (g << 6);    // wave-uniform -> s_load
#pragma unroll
    for (int o = 0; o < 64; ++o) acc[o] = fmaf(wr[o], vv, acc[o]);
  }
  float* ob = out + ((size_t)b * 64) * NPOS + p;
#pragma unroll
  for (int o = 0; o < 64; ++o) ob[(size_t)o * NPOS] = acc[o];
}

extern "C" void kernel_launch(void* const* d_in, const int* in_sizes, int n_in,
                              void* d_out, int out_size, void* d_ws, size_t ws_size,
                              hipStream_t stream) {
  const float* x      = (const float*)d_in[0];
  const float* w_qkv  = (const float*)d_in[1];
  const float* w_dw   = (const float*)d_in[2];
  const float* temp   = (const float*)d_in[3];
  const float* w_proj = (const float*)d_in[4];
  float* out = (float*)d_out;   // also used as pre-conv staging per group
  float* ws  = (float*)d_ws;

  // workspace layout (floats) — total ~64.5 MiB
  float* conv_buf = ws;                       // 16,777,216  (qconv, later vconv)
  float* nqp      = conv_buf + 16777216ull;   // 8,192
  float* partial9 = nqp + 8192ull;            // 128*64*9 = 73,728
  float* Abuf     = partial9 + 73728ull;      // 1,024
  float* MTbuf    = Abuf + 1024ull;           // 8,192
  float* wTbuf    = MTbuf + 8192ull;          // 12,288

  k_prep<<<2, 256, 0, stream>>>(w_qkv, wTbuf);
  // q group: pointwise -> d_out, depthwise -> conv_buf (+ nq partials)
  k_pw<<<dim3(512, 2), 256, 0, stream>>>(x, wTbuf, out);
  k_dw<<<dim3(4, 16, 128), dim3(32, 8), 0, stream>>>(out, w_dw, conv_buf, nqp, 0);
  // k group: pointwise -> d_out, depthwise fused with column-Gram vs qconv
  k_pw<<<dim3(512, 2), 256, 0, stream>>>(x, wTbuf + 4096, out);
  k_dwk2<<<dim3(4, 16, 64), dim3(32, 8), 0, stream>>>(out, conv_buf, w_dw, partial9);
  // attention matrix + folded projection matrix
  k_attn<<<16, 128, 0, stream>>>(partial9, nqp, temp, Abuf);
  k_M<<<2, 256, 0, stream>>>(w_proj, Abuf, MTbuf);
  // v group: pointwise -> d_out, depthwise -> conv_buf, apply M -> d_out
  k_pw<<<dim3(512, 2), 256, 0, stream>>>(x, wTbuf + 8192, out);
  k_dw<<<dim3(4, 16, 128), dim3(32, 8), 0, stream>>>(out, w_dw, conv_buf, nullptr, 2);
  k_out<<<dim3(512, 2), 256, 0, stream>>>(conv_buf, MTbuf, out);
}

// Round 7
// 321.250 us; speedup vs baseline: 1.4508x; 1.0789x over previous
//
#include <hip/hip_runtime.h>
#include <math.h>

#define NPOS 131072  // 8*128*128 spatial positions per (b, channel)

// ---------------------------------------------------------------------------
// k_prep: transpose w_qkv [192 out][64 in] -> wT[3 g][64 k][64 o] so the
// pointwise kernels can read weight rows with wave-uniform (scalar) loads.
// ---------------------------------------------------------------------------
__global__ void k_prep(const float* __restrict__ w_qkv, float* __restrict__ wT) {
  for (int i = blockIdx.x * 256 + threadIdx.x; i < 12288; i += 512) {
    int g = i >> 12, r = i & 4095, k = r >> 6, o = r & 63;
    wT[i] = w_qkv[(g * 64 + o) * 64 + k];
  }
}

// ---------------------------------------------------------------------------
// k_pw: pre[b][o][p] = sum_k wTg[k][o] * x[b][k][p].  grid (512, 2), block 256.
// Weights via wave-uniform loads (SGPR operands) -> zero LDS traffic.
// ---------------------------------------------------------------------------
__global__ __launch_bounds__(256) void k_pw(const float* __restrict__ x,
                                            const float* __restrict__ wTg,
                                            float* __restrict__ pre) {
  const int p = blockIdx.x * 256 + threadIdx.x;
  const int b = blockIdx.y;
  float acc[64];
#pragma unroll
  for (int o = 0; o < 64; ++o) acc[o] = 0.f;
  const float* xb = x + ((size_t)b * 64) * NPOS + p;
  for (int k = 0; k < 64; ++k) {
    float xv = xb[(size_t)k * NPOS];
    const float* wr = wTg + (k << 6);   // wave-uniform row -> s_load
#pragma unroll
    for (int o = 0; o < 64; ++o) acc[o] = fmaf(wr[o], xv, acc[o]);
  }
  float* ob = pre + ((size_t)b * 64) * NPOS + p;
#pragma unroll
  for (int o = 0; o < 64; ++o) ob[(size_t)o * NPOS] = acc[o];
}

// ---------------------------------------------------------------------------
// stage_tile: load one channel's halo tile into LDS t[10][10][40].
// d-planes 0 and 9 are zero (depth halo), h halo via bounds check, w: center
// 32 floats at [4..35] via aligned float4 (w0 % 32 == 0), edges at [3]
// (w0-1) and [36] (w0+32) scalar.
// ---------------------------------------------------------------------------
__device__ __forceinline__ void stage_tile(float (*t)[10][40], const float* __restrict__ in,
                                           int h0, int w0, int tid) {
  for (int i = tid; i < 800; i += 256) {
    int j = i & 7, row = i >> 3;          // 8 float4 per row, 100 rows
    int h = row % 10, dpl = row / 10;     // dpl 0..9 (= depth+1)
    int dd = dpl - 1, hh = h0 + h - 1;
    float4 v = make_float4(0.f, 0.f, 0.f, 0.f);
    if (dd >= 0 && dd < 8 && hh >= 0 && hh < 128)
      v = *(const float4*)&in[((size_t)dd * 128 + hh) * 128 + (w0 + j * 4)];
    *(float4*)&t[dpl][h][4 + j * 4] = v;
  }
  for (int i = tid; i < 200; i += 256) {
    int side = i & 1, row = i >> 1;
    int h = row % 10, dpl = row / 10;
    int dd = dpl - 1, hh = h0 + h - 1;
    int ww = side ? (w0 + 32) : (w0 - 1);
    float v = 0.f;
    if (dd >= 0 && dd < 8 && hh >= 0 && hh < 128 && ww >= 0 && ww < 128)
      v = in[((size_t)dd * 128 + hh) * 128 + ww];
    t[dpl][h][side ? 36 : 3] = v;
  }
}

// ---------------------------------------------------------------------------
// conv_droll: d-rolling 3x3x3 conv at (hl, wl) for all 8 d-outputs.
// One pass over the 10 staged planes: 90 LDS reads (vs 216 naive), 216 FMA.
// Same conflict-free lane pattern as the naive version (lanes span wl 0..31).
// ---------------------------------------------------------------------------
__device__ __forceinline__ void conv_droll(const float (*t)[10][40], const float* wk,
                                           int hl, int wl, float* acc) {
#pragma unroll
  for (int d = 0; d < 8; ++d) acc[d] = 0.f;
#pragma unroll
  for (int dpl = 0; dpl < 10; ++dpl) {
#pragma unroll
    for (int kh = 0; kh < 3; ++kh) {
#pragma unroll
      for (int kw = 0; kw < 3; ++kw) {
        float f = t[dpl][hl + kh][3 + wl + kw];
#pragma unroll
        for (int kd = 0; kd < 3; ++kd) {
          const int d = dpl - kd;  // output plane using staged plane dpl at tap kd
          if (d >= 0 && d < 8)
            acc[d] = fmaf(f, wk[(kd * 3 + kh) * 3 + kw], acc[d]);
        }
      }
    }
  }
}

// ---------------------------------------------------------------------------
// k_dw: depthwise 3x3x3 SAME on a 64-channel group (weights rows g*64..+63).
// grid (4, 16, 128), block (32, 8). Optional per-block sum-of-squares -> nqp.
// ---------------------------------------------------------------------------
__global__ __launch_bounds__(256) void k_dw(const float* __restrict__ pre,
                                            const float* __restrict__ w_dw,
                                            float* __restrict__ conv,
                                            float* __restrict__ nqp, int g) {
  const int b = blockIdx.z >> 6;
  const int c = blockIdx.z & 63;
  const int h0 = blockIdx.y * 8;
  const int w0 = blockIdx.x * 32;
  __shared__ float t[10][10][40];
  __shared__ float red[4];
  const int tid = threadIdx.y * 32 + threadIdx.x;
  stage_tile(t, pre + ((size_t)b * 64 + c) * NPOS, h0, w0, tid);
  float wk[27];
#pragma unroll
  for (int i = 0; i < 27; ++i) wk[i] = w_dw[(g * 64 + c) * 27 + i];  // uniform -> SGPR
  __syncthreads();
  const int wl = threadIdx.x, hl = threadIdx.y;
  float acc[8];
  conv_droll(t, wk, hl, wl, acc);
  float* outp = conv + ((size_t)b * 64 + c) * NPOS + (size_t)(h0 + hl) * 128 + (w0 + wl);
  float nsum = 0.f;
#pragma unroll
  for (int d = 0; d < 8; ++d) {
    outp[(size_t)d * 16384] = acc[d];
    nsum = fmaf(acc[d], acc[d], nsum);
  }
  if (nqp) {
    const int lane = tid & 63, wv = tid >> 6;
    float v = nsum;
    v += __shfl_down(v, 32); v += __shfl_down(v, 16); v += __shfl_down(v, 8);
    v += __shfl_down(v, 4);  v += __shfl_down(v, 2);  v += __shfl_down(v, 1);
    if (lane == 0) red[wv] = v;
    __syncthreads();
    if (tid == 0) {
      const int blk = blockIdx.y * 4 + blockIdx.x;
      nqp[((size_t)b * 64 + c) * 64 + blk] = red[0] + red[1] + red[2] + red[3];
    }
  }
}

// ---------------------------------------------------------------------------
// k_gram: depthwise-conv ONE k-channel (d-rolling) and dot the 8 conv outputs
// against the head's 8 q-channels -> partial column S[c] (8) + nk (1).
// Flat grid 8192, XCD-swizzled: assuming id%8 -> XCD, each XCD streams 2
// (b,head) slabs consecutively so the 4 MB q-slice stays L2-resident across
// its 8x re-reads. block (32, 8).
// partial9[((b*64+ch)*64 + blk)*9 + i]: i<8 -> S[c=i], i==8 -> nk.
// ---------------------------------------------------------------------------
__global__ __launch_bounds__(256) void k_gram(const float* __restrict__ kpre,
                                              const float* __restrict__ qconv,
                                              const float* __restrict__ w_dw,
                                              float* __restrict__ partial9) {
  const int i = blockIdx.x;                 // 0..8191
  const int slot = i & 7, j = i >> 3;       // slot -> XCD (id%8 round-robin)
  const int hg = slot * 2 + (j >> 9);       // 2 head-globals per XCD, sequential
  const int ch8 = (j >> 6) & 7;
  const int blk = j & 63;
  const int b = hg >> 3, head = hg & 7;
  const int ch = head * 8 + ch8;
  const int by = blk >> 2, bx = blk & 3;
  const int h0 = by * 8;
  const int w0 = bx * 32;
  __shared__ float t[10][10][40];
  __shared__ float red[4][9];
  const int tid = threadIdx.y * 32 + threadIdx.x;
  stage_tile(t, kpre + ((size_t)b * 64 + ch) * NPOS, h0, w0, tid);
  float wk[27];
#pragma unroll
  for (int i2 = 0; i2 < 27; ++i2) wk[i2] = w_dw[(64 + ch) * 27 + i2];  // uniform -> SGPR
  __syncthreads();
  const int wl = threadIdx.x, hl = threadIdx.y;
  float a[8];
  conv_droll(t, wk, hl, wl, a);
  float nk = 0.f;
#pragma unroll
  for (int d = 0; d < 8; ++d) nk = fmaf(a[d], a[d], nk);
  const float* qb = qconv + ((size_t)b * 64 + head * 8) * NPOS +
                    (size_t)(h0 + hl) * 128 + (w0 + wl);
  float S[8];
#pragma unroll
  for (int c = 0; c < 8; ++c) {
    const float* qc = qb + (size_t)c * NPOS;
    float s = 0.f;
#pragma unroll
    for (int d = 0; d < 8; ++d) s = fmaf(qc[(size_t)d * 16384], a[d], s);
    S[c] = s;
  }
  const int lane = tid & 63, wv = tid >> 6;
#pragma unroll
  for (int i2 = 0; i2 < 9; ++i2) {
    float v = (i2 < 8) ? S[i2] : nk;
    v += __shfl_down(v, 32); v += __shfl_down(v, 16); v += __shfl_down(v, 8);
    v += __shfl_down(v, 4);  v += __shfl_down(v, 2);  v += __shfl_down(v, 1);
    if (lane == 0) red[wv][i2] = v;
  }
  __syncthreads();
  if (tid < 9) {
    float s = red[0][tid] + red[1][tid] + red[2][tid] + red[3][tid];
    partial9[(((size_t)b * 64 + ch) * 64 + blk) * 9 + tid] = s;
  }
}

// ---------------------------------------------------------------------------
// k_attn: reduce partials, l2-normalize, temperature, softmax -> A[bh][c][e].
// grid 16, block 128.
// ---------------------------------------------------------------------------
__global__ void k_attn(const float* __restrict__ partial9, const float* __restrict__ nqp,
                       const float* __restrict__ temp, float* __restrict__ A) {
  const int bh = blockIdx.x;
  const int b = bh >> 3, head = bh & 7;
  const int tid = threadIdx.x;
  __shared__ float sums[80];
  if (tid < 64) {
    const int c = tid >> 3, e = tid & 7;
    float s = 0.f;
    const float* pp = partial9 + (((size_t)b * 64 + head * 8 + e) * 64) * 9 + c;
    for (int j = 0; j < 64; ++j) s += pp[j * 9];
    sums[c * 8 + e] = s;
  } else if (tid < 72) {
    const int e = tid - 64;
    float s = 0.f;
    const float* pp = partial9 + (((size_t)b * 64 + head * 8 + e) * 64) * 9 + 8;
    for (int j = 0; j < 64; ++j) s += pp[j * 9];
    sums[64 + e] = s;  // nk[e]
  } else if (tid < 80) {
    const int c = tid - 72;
    float s = 0.f;
    const float* pp = nqp + ((size_t)b * 64 + head * 8 + c) * 64;
    for (int j = 0; j < 64; ++j) s += pp[j];
    sums[72 + c] = s;  // nq[c]
  }
  __syncthreads();
  if (tid < 8) {
    const int c = tid;
    float tp = temp[head];
    float qd = fmaxf(sqrtf(sums[72 + c]), 1e-12f);
    float vals[8];
    float mx = -1e30f;
#pragma unroll
    for (int e = 0; e < 8; ++e) {
      float kd = fmaxf(sqrtf(sums[64 + e]), 1e-12f);
      vals[e] = sums[c * 8 + e] / (qd * kd) * tp;
      mx = fmaxf(mx, vals[e]);
    }
    float den = 0.f;
#pragma unroll
    for (int e = 0; e < 8; ++e) { vals[e] = expf(vals[e] - mx); den += vals[e]; }
#pragma unroll
    for (int e = 0; e < 8; ++e) A[bh * 64 + c * 8 + e] = vals[e] / den;
  }
}

// ---------------------------------------------------------------------------
// k_M: M_b[o][hg*8+j] = sum_i Wp[o][hg*8+i] * A[b][hg][i][j]; writes the
// transposed MT[b][g][o] for scalar-load consumption in k_out. grid 2, blk 256.
// ---------------------------------------------------------------------------
__global__ void k_M(const float* __restrict__ w_proj, const float* __restrict__ A,
                    float* __restrict__ MT) {
  const int b = blockIdx.x;
  for (int e = threadIdx.x; e < 4096; e += 256) {
    int o = e >> 6, gch = e & 63;
    int hg = gch >> 3, j = gch & 7;
    float s = 0.f;
#pragma unroll
    for (int i = 0; i < 8; ++i)
      s += w_proj[o * 64 + hg * 8 + i] * A[(b * 8 + hg) * 64 + i * 8 + j];
    MT[b * 4096 + gch * 64 + o] = s;
  }
}

// ---------------------------------------------------------------------------
// k_out: out[b][o][p] = sum_g MT[b][g][o] * vconv[b][g][p]. Same scalar-weight
// structure as k_pw. grid (512, 2), block 256.
// ---------------------------------------------------------------------------
__global__ __launch_bounds__(256) void k_out(const float* __restrict__ vconv,
                                             const float* __restrict__ MT,
                                             float* __restrict__ out) {
  const int p = blockIdx.x * 256 + threadIdx.x;
  const int b = blockIdx.y;
  float acc[64];
#pragma unroll
  for (int o = 0; o < 64; ++o) acc[o] = 0.f;
  const float* vb = vconv + ((size_t)b * 64) * NPOS + p;
  const float* Mb = MT + b * 4096;
  for (int g = 0; g < 64; ++g) {
    float vv = vb[(size_t)g * NPOS];
    const float* wr = Mb + (g << 6);    // wave-uniform -> s_load
#pragma unroll
    for (int o = 0; o < 64; ++o) acc[o] = fmaf(wr[o], vv, acc[o]);
  }
  float* ob = out + ((size_t)b * 64) * NPOS + p;
#pragma unroll
  for (int o = 0; o < 64; ++o) ob[(size_t)o * NPOS] = acc[o];
}

extern "C" void kernel_launch(void* const* d_in, const int* in_sizes, int n_in,
                              void* d_out, int out_size, void* d_ws, size_t ws_size,
                              hipStream_t stream) {
  const float* x      = (const float*)d_in[0];
  const float* w_qkv  = (const float*)d_in[1];
  const float* w_dw   = (const float*)d_in[2];
  const float* temp   = (const float*)d_in[3];
  const float* w_proj = (const float*)d_in[4];
  float* out = (float*)d_out;   // also used as pre-conv staging per group
  float* ws  = (float*)d_ws;

  // workspace layout (floats) — total ~64.5 MiB
  float* conv_buf = ws;                       // 16,777,216  (qconv, later vconv)
  float* nqp      = conv_buf + 16777216ull;   // 8,192
  float* partial9 = nqp + 8192ull;            // 128*64*9 = 73,728
  float* Abuf     = partial9 + 73728ull;      // 1,024
  float* MTbuf    = Abuf + 1024ull;           // 8,192
  float* wTbuf    = MTbuf + 8192ull;          // 12,288

  k_prep<<<2, 256, 0, stream>>>(w_qkv, wTbuf);
  // q group: pointwise -> d_out, depthwise -> conv_buf (+ nq partials)
  k_pw<<<dim3(512, 2), 256, 0, stream>>>(x, wTbuf, out);
  k_dw<<<dim3(4, 16, 128), dim3(32, 8), 0, stream>>>(out, w_dw, conv_buf, nqp, 0);
  // k group: pointwise -> d_out, depthwise fused with column-Gram vs qconv
  k_pw<<<dim3(512, 2), 256, 0, stream>>>(x, wTbuf + 4096, out);
  k_gram<<<8192, dim3(32, 8), 0, stream>>>(out, conv_buf, w_dw, partial9);
  // attention matrix + folded projection matrix
  k_attn<<<16, 128, 0, stream>>>(partial9, nqp, temp, Abuf);
  k_M<<<2, 256, 0, stream>>>(w_proj, Abuf, MTbuf);
  // v group: pointwise -> d_out, depthwise -> conv_buf, apply M -> d_out
  k_pw<<<dim3(512, 2), 256, 0, stream>>>(x, wTbuf + 8192, out);
  k_dw<<<dim3(4, 16, 128), dim3(32, 8), 0, stream>>>(out, w_dw, conv_buf, nullptr, 2);
  k_out<<<dim3(512, 2), 256, 0, stream>>>(conv_buf, MTbuf, out);
}

// Round 8
// 293.226 us; speedup vs baseline: 1.5895x; 1.0956x over previous
//
#include <hip/hip_runtime.h>
#include <math.h>

#define NPOS 131072  // 8*128*128 spatial positions per (b, channel)

// ---------------------------------------------------------------------------
// k_prep: transpose w_qkv [192 out][64 in] -> wT[3 g][64 k][64 o] so the
// pointwise kernels can read weight rows with wave-uniform (scalar) loads.
// ---------------------------------------------------------------------------
__global__ void k_prep(const float* __restrict__ w_qkv, float* __restrict__ wT) {
  for (int i = blockIdx.x * 256 + threadIdx.x; i < 12288; i += 512) {
    int g = i >> 12, r = i & 4095, k = r >> 6, o = r & 63;
    wT[i] = w_qkv[(g * 64 + o) * 64 + k];
  }
}

// ---------------------------------------------------------------------------
// k_pw: pre[b][o][p] = sum_k wTg[k][o] * x[b][k][p].  grid (512, 2), block 256.
// Weights via wave-uniform loads (SGPR operands) -> zero LDS traffic.
// ---------------------------------------------------------------------------
__global__ __launch_bounds__(256) void k_pw(const float* __restrict__ x,
                                            const float* __restrict__ wTg,
                                            float* __restrict__ pre) {
  const int p = blockIdx.x * 256 + threadIdx.x;
  const int b = blockIdx.y;
  float acc[64];
#pragma unroll
  for (int o = 0; o < 64; ++o) acc[o] = 0.f;
  const float* xb = x + ((size_t)b * 64) * NPOS + p;
  for (int k = 0; k < 64; ++k) {
    float xv = xb[(size_t)k * NPOS];
    const float* wr = wTg + (k << 6);   // wave-uniform row -> s_load
#pragma unroll
    for (int o = 0; o < 64; ++o) acc[o] = fmaf(wr[o], xv, acc[o]);
  }
  float* ob = pre + ((size_t)b * 64) * NPOS + p;
#pragma unroll
  for (int o = 0; o < 64; ++o) ob[(size_t)o * NPOS] = acc[o];
}

// ---------------------------------------------------------------------------
// stage_tile: load one channel's halo tile into LDS t[10][10][40].
// d-planes 0 and 9 are zero (depth halo), h halo via bounds check, w: center
// 32 floats at [4..35] via aligned float4 (w0 % 32 == 0), edges at [3]
// (w0-1) and [36] (w0+32) scalar.
// ---------------------------------------------------------------------------
__device__ __forceinline__ void stage_tile(float (*t)[10][40], const float* __restrict__ in,
                                           int h0, int w0, int tid) {
  for (int i = tid; i < 800; i += 256) {
    int j = i & 7, row = i >> 3;          // 8 float4 per row, 100 rows
    int h = row % 10, dpl = row / 10;     // dpl 0..9 (= depth+1)
    int dd = dpl - 1, hh = h0 + h - 1;
    float4 v = make_float4(0.f, 0.f, 0.f, 0.f);
    if (dd >= 0 && dd < 8 && hh >= 0 && hh < 128)
      v = *(const float4*)&in[((size_t)dd * 128 + hh) * 128 + (w0 + j * 4)];
    *(float4*)&t[dpl][h][4 + j * 4] = v;
  }
  for (int i = tid; i < 200; i += 256) {
    int side = i & 1, row = i >> 1;
    int h = row % 10, dpl = row / 10;
    int dd = dpl - 1, hh = h0 + h - 1;
    int ww = side ? (w0 + 32) : (w0 - 1);
    float v = 0.f;
    if (dd >= 0 && dd < 8 && hh >= 0 && hh < 128 && ww >= 0 && ww < 128)
      v = in[((size_t)dd * 128 + hh) * 128 + ww];
    t[dpl][h][side ? 36 : 3] = v;
  }
}

// ---------------------------------------------------------------------------
// conv_droll: d-rolling 3x3x3 conv at (hl, wl) for all 8 d-outputs.
// One pass over the 10 staged planes: 90 LDS reads (vs 216 naive), 216 FMA.
// ---------------------------------------------------------------------------
__device__ __forceinline__ void conv_droll(const float (*t)[10][40], const float* wk,
                                           int hl, int wl, float* acc) {
#pragma unroll
  for (int d = 0; d < 8; ++d) acc[d] = 0.f;
#pragma unroll
  for (int dpl = 0; dpl < 10; ++dpl) {
#pragma unroll
    for (int kh = 0; kh < 3; ++kh) {
#pragma unroll
      for (int kw = 0; kw < 3; ++kw) {
        float f = t[dpl][hl + kh][3 + wl + kw];
#pragma unroll
        for (int kd = 0; kd < 3; ++kd) {
          const int d = dpl - kd;  // output plane using staged plane dpl at tap kd
          if (d >= 0 && d < 8)
            acc[d] = fmaf(f, wk[(kd * 3 + kh) * 3 + kw], acc[d]);
        }
      }
    }
  }
}

// ---------------------------------------------------------------------------
// k_dw: depthwise 3x3x3 SAME on a 64-channel group (weights rows g*64..+63).
// Flat grid 8192, XCD-swizzled (each XCD owns 16 whole channels -> spatial
// halo re-reads hit local L2). block (32, 8). Optional sum-of-squares -> nqp.
// ---------------------------------------------------------------------------
__global__ __launch_bounds__(256) void k_dw(const float* __restrict__ pre,
                                            const float* __restrict__ w_dw,
                                            float* __restrict__ conv,
                                            float* __restrict__ nqp, int g) {
  const int id = blockIdx.x;                    // 0..8191
  const int sid = (id & 7) * 1024 + (id >> 3);  // XCD-contiguous chunks
  const int z = sid >> 6, r = sid & 63, by = r >> 2, bx = r & 3;
  const int b = z >> 6;
  const int c = z & 63;
  const int h0 = by * 8;
  const int w0 = bx * 32;
  __shared__ float t[10][10][40];
  __shared__ float red[4];
  const int tid = threadIdx.y * 32 + threadIdx.x;
  stage_tile(t, pre + ((size_t)b * 64 + c) * NPOS, h0, w0, tid);
  float wk[27];
#pragma unroll
  for (int i = 0; i < 27; ++i) wk[i] = w_dw[(g * 64 + c) * 27 + i];  // uniform -> SGPR
  __syncthreads();
  const int wl = threadIdx.x, hl = threadIdx.y;
  float acc[8];
  conv_droll(t, wk, hl, wl, acc);
  float* outp = conv + ((size_t)b * 64 + c) * NPOS + (size_t)(h0 + hl) * 128 + (w0 + wl);
  float nsum = 0.f;
#pragma unroll
  for (int d = 0; d < 8; ++d) {
    outp[(size_t)d * 16384] = acc[d];
    nsum = fmaf(acc[d], acc[d], nsum);
  }
  if (nqp) {
    const int lane = tid & 63, wv = tid >> 6;
    float v = nsum;
    v += __shfl_down(v, 32); v += __shfl_down(v, 16); v += __shfl_down(v, 8);
    v += __shfl_down(v, 4);  v += __shfl_down(v, 2);  v += __shfl_down(v, 1);
    if (lane == 0) red[wv] = v;
    __syncthreads();
    if (tid == 0) {
      const int blk = by * 4 + bx;
      nqp[((size_t)b * 64 + c) * 64 + blk] = red[0] + red[1] + red[2] + red[3];
    }
  }
}

// ---------------------------------------------------------------------------
// k_gram: depthwise-conv ONE k-channel (d-rolling) and dot the 8 conv outputs
// against the head's 8 q-channels. The 64 q values are PREFETCHED into
// registers between staging and the barrier (r7: compiler left them at use
// sites -> exposed L2 latency, VALUBusy 46%). sched_barrier(0) pins them.
// Flat grid 8192, XCD-swizzled. block (32, 8).
// partial9[((b*64+ch)*64 + blk)*9 + i]: i<8 -> S[c=i], i==8 -> nk.
// ---------------------------------------------------------------------------
__global__ __launch_bounds__(256) void k_gram(const float* __restrict__ kpre,
                                              const float* __restrict__ qconv,
                                              const float* __restrict__ w_dw,
                                              float* __restrict__ partial9) {
  const int i = blockIdx.x;                 // 0..8191
  const int slot = i & 7, j = i >> 3;       // slot -> XCD (id%8 round-robin)
  const int hg = slot * 2 + (j >> 9);       // 2 head-globals per XCD, sequential
  const int ch8 = (j >> 6) & 7;
  const int blk = j & 63;
  const int b = hg >> 3, head = hg & 7;
  const int ch = head * 8 + ch8;
  const int by = blk >> 2, bx = blk & 3;
  const int h0 = by * 8;
  const int w0 = bx * 32;
  __shared__ float t[10][10][40];
  __shared__ float red[4][9];
  const int tid = threadIdx.y * 32 + threadIdx.x;
  const int wl = threadIdx.x, hl = threadIdx.y;
  stage_tile(t, kpre + ((size_t)b * 64 + ch) * NPOS, h0, w0, tid);
  float wk[27];
#pragma unroll
  for (int i2 = 0; i2 < 27; ++i2) wk[i2] = w_dw[(64 + ch) * 27 + i2];  // uniform -> SGPR
  // Prefetch q into registers AFTER the staging loads (so the barrier's
  // vmcnt(0) drain overlaps them) and BEFORE the conv.
  float qv[64];
  {
    const float* qb = qconv + ((size_t)b * 64 + head * 8) * NPOS +
                      (size_t)(h0 + hl) * 128 + (w0 + wl);
#pragma unroll
    for (int c = 0; c < 8; ++c)
#pragma unroll
      for (int d = 0; d < 8; ++d)
        qv[c * 8 + d] = qb[(size_t)c * NPOS + (size_t)d * 16384];
  }
  __builtin_amdgcn_sched_barrier(0);  // don't sink the q loads past here
  __syncthreads();
  float a[8];
  conv_droll(t, wk, hl, wl, a);
  float nk = 0.f;
#pragma unroll
  for (int d = 0; d < 8; ++d) nk = fmaf(a[d], a[d], nk);
  float S[8];
#pragma unroll
  for (int c = 0; c < 8; ++c) {
    float s = 0.f;
#pragma unroll
    for (int d = 0; d < 8; ++d) s = fmaf(qv[c * 8 + d], a[d], s);
    S[c] = s;
  }
  const int lane = tid & 63, wv = tid >> 6;
#pragma unroll
  for (int i2 = 0; i2 < 9; ++i2) {
    float v = (i2 < 8) ? S[i2] : nk;
    v += __shfl_down(v, 32); v += __shfl_down(v, 16); v += __shfl_down(v, 8);
    v += __shfl_down(v, 4);  v += __shfl_down(v, 2);  v += __shfl_down(v, 1);
    if (lane == 0) red[wv][i2] = v;
  }
  __syncthreads();
  if (tid < 9) {
    float s = red[0][tid] + red[1][tid] + red[2][tid] + red[3][tid];
    partial9[(((size_t)b * 64 + ch) * 64 + blk) * 9 + tid] = s;
  }
}

// ---------------------------------------------------------------------------
// k_attn: reduce partials, l2-normalize, temperature, softmax -> A[bh][c][e].
// grid 16, block 128.
// ---------------------------------------------------------------------------
__global__ void k_attn(const float* __restrict__ partial9, const float* __restrict__ nqp,
                       const float* __restrict__ temp, float* __restrict__ A) {
  const int bh = blockIdx.x;
  const int b = bh >> 3, head = bh & 7;
  const int tid = threadIdx.x;
  __shared__ float sums[80];
  if (tid < 64) {
    const int c = tid >> 3, e = tid & 7;
    float s = 0.f;
    const float* pp = partial9 + (((size_t)b * 64 + head * 8 + e) * 64) * 9 + c;
    for (int j = 0; j < 64; ++j) s += pp[j * 9];
    sums[c * 8 + e] = s;
  } else if (tid < 72) {
    const int e = tid - 64;
    float s = 0.f;
    const float* pp = partial9 + (((size_t)b * 64 + head * 8 + e) * 64) * 9 + 8;
    for (int j = 0; j < 64; ++j) s += pp[j * 9];
    sums[64 + e] = s;  // nk[e]
  } else if (tid < 80) {
    const int c = tid - 72;
    float s = 0.f;
    const float* pp = nqp + ((size_t)b * 64 + head * 8 + c) * 64;
    for (int j = 0; j < 64; ++j) s += pp[j];
    sums[72 + c] = s;  // nq[c]
  }
  __syncthreads();
  if (tid < 8) {
    const int c = tid;
    float tp = temp[head];
    float qd = fmaxf(sqrtf(sums[72 + c]), 1e-12f);
    float vals[8];
    float mx = -1e30f;
#pragma unroll
    for (int e = 0; e < 8; ++e) {
      float kd = fmaxf(sqrtf(sums[64 + e]), 1e-12f);
      vals[e] = sums[c * 8 + e] / (qd * kd) * tp;
      mx = fmaxf(mx, vals[e]);
    }
    float den = 0.f;
#pragma unroll
    for (int e = 0; e < 8; ++e) { vals[e] = expf(vals[e] - mx); den += vals[e]; }
#pragma unroll
    for (int e = 0; e < 8; ++e) A[bh * 64 + c * 8 + e] = vals[e] / den;
  }
}

// ---------------------------------------------------------------------------
// k_M: M_b[o][hg*8+j] = sum_i Wp[o][hg*8+i] * A[b][hg][i][j]; writes the
// transposed MT[b][g][o] for scalar-load consumption in k_out. grid 2, blk 256.
// ---------------------------------------------------------------------------
__global__ void k_M(const float* __restrict__ w_proj, const float* __restrict__ A,
                    float* __restrict__ MT) {
  const int b = blockIdx.x;
  for (int e = threadIdx.x; e < 4096; e += 256) {
    int o = e >> 6, gch = e & 63;
    int hg = gch >> 3, j = gch & 7;
    float s = 0.f;
#pragma unroll
    for (int i = 0; i < 8; ++i)
      s += w_proj[o * 64 + hg * 8 + i] * A[(b * 8 + hg) * 64 + i * 8 + j];
    MT[b * 4096 + gch * 64 + o] = s;
  }
}

// ---------------------------------------------------------------------------
// k_out: out[b][o][p] = sum_g MT[b][g][o] * vconv[b][g][p]. Same scalar-weight
// structure as k_pw. grid (512, 2), block 256.
// ---------------------------------------------------------------------------
__global__ __launch_bounds__(256) void k_out(const float* __restrict__ vconv,
                                             const float* __restrict__ MT,
                                             float* __restrict__ out) {
  const int p = blockIdx.x * 256 + threadIdx.x;
  const int b = blockIdx.y;
  float acc[64];
#pragma unroll
  for (int o = 0; o < 64; ++o) acc[o] = 0.f;
  const float* vb = vconv + ((size_t)b * 64) * NPOS + p;
  const float* Mb = MT + b * 4096;
  for (int g = 0; g < 64; ++g) {
    float vv = vb[(size_t)g * NPOS];
    const float* wr = Mb + (g << 6);    // wave-uniform -> s_load
#pragma unroll
    for (int o = 0; o < 64; ++o) acc[o] = fmaf(wr[o], vv, acc[o]);
  }
  float* ob = out + ((size_t)b * 64) * NPOS + p;
#pragma unroll
  for (int o = 0; o < 64; ++o) ob[(size_t)o * NPOS] = acc[o];
}

extern "C" void kernel_launch(void* const* d_in, const int* in_sizes, int n_in,
                              void* d_out, int out_size, void* d_ws, size_t ws_size,
                              hipStream_t stream) {
  const float* x      = (const float*)d_in[0];
  const float* w_qkv  = (const float*)d_in[1];
  const float* w_dw   = (const float*)d_in[2];
  const float* temp   = (const float*)d_in[3];
  const float* w_proj = (const float*)d_in[4];
  float* out = (float*)d_out;   // also used as pre-conv staging per group
  float* ws  = (float*)d_ws;

  // workspace layout (floats) — total ~64.5 MiB
  float* conv_buf = ws;                       // 16,777,216  (qconv, later vconv)
  float* nqp      = conv_buf + 16777216ull;   // 8,192
  float* partial9 = nqp + 8192ull;            // 128*64*9 = 73,728
  float* Abuf     = partial9 + 73728ull;      // 1,024
  float* MTbuf    = Abuf + 1024ull;           // 8,192
  float* wTbuf    = MTbuf + 8192ull;          // 12,288

  k_prep<<<2, 256, 0, stream>>>(w_qkv, wTbuf);
  // q group: pointwise -> d_out, depthwise -> conv_buf (+ nq partials)
  k_pw<<<dim3(512, 2), 256, 0, stream>>>(x, wTbuf, out);
  k_dw<<<8192, dim3(32, 8), 0, stream>>>(out, w_dw, conv_buf, nqp, 0);
  // k group: pointwise -> d_out, depthwise fused with column-Gram vs qconv
  k_pw<<<dim3(512, 2), 256, 0, stream>>>(x, wTbuf + 4096, out);
  k_gram<<<8192, dim3(32, 8), 0, stream>>>(out, conv_buf, w_dw, partial9);
  // attention matrix + folded projection matrix
  k_attn<<<16, 128, 0, stream>>>(partial9, nqp, temp, Abuf);
  k_M<<<2, 256, 0, stream>>>(w_proj, Abuf, MTbuf);
  // v group: pointwise -> d_out, depthwise -> conv_buf, apply M -> d_out
  k_pw<<<dim3(512, 2), 256, 0, stream>>>(x, wTbuf + 8192, out);
  k_dw<<<8192, dim3(32, 8), 0, stream>>>(out, w_dw, conv_buf, nullptr, 2);
  k_out<<<dim3(512, 2), 256, 0, stream>>>(conv_buf, MTbuf, out);
}